// Round 2
// baseline (375.829 us; speedup 1.0000x reference)
//
#include <hip/hip_runtime.h>

#define B_DIM 16
#define C_DIM 256
#define K_DIM 4096

#define TI 64
#define TJ 64
#define BK 32
#define LROW 68   // 64 + 4 pad: keeps 16B alignment for ds_read_b128, breaks bank stride

// ---------------- Phase 1: candidate row norms ny[b*C+j] = ||y_j||^2 ----------------
__global__ __launch_bounds__(64) void norms_kernel(const float* __restrict__ y,
                                                   float* __restrict__ ny) {
    const int row = blockIdx.x;  // b*C + j, 4096 rows
    const float4* src = (const float4*)(y + (size_t)row * K_DIM);
    float s = 0.f;
    for (int i = threadIdx.x; i < K_DIM / 4; i += 64) {
        float4 v = src[i];
        s += v.x * v.x + v.y * v.y + v.z * v.z + v.w * v.w;
    }
#pragma unroll
    for (int m = 32; m; m >>= 1) s += __shfl_xor(s, m, 64);
    if (threadIdx.x == 0) ny[row] = s;
}

// ---------------- Phase 2: tiled gram + fused per-row argmin over 64-col tile ----------------
__global__ __launch_bounds__(256) void gram_argmin_kernel(
        const float* __restrict__ x, const float* __restrict__ y,
        const float* __restrict__ ny,
        float* __restrict__ pval, int* __restrict__ pidx) {
    const int t  = threadIdx.x;
    const int tx = t & 15;       // column group (j)
    const int ty = t >> 4;       // row group (i), 0..15
    const int jt = blockIdx.x;   // 0..3
    const int it = blockIdx.y;   // 0..3
    const int b  = blockIdx.z;   // 0..15

    const float* __restrict__ xb = x + ((size_t)b * C_DIM + it * TI) * K_DIM;
    const float* __restrict__ yb = y + ((size_t)b * C_DIM + jt * TJ) * K_DIM;

    __shared__ float As[BK][LROW];  // k-major: As[k][i]
    __shared__ float Bs[BK][LROW];  // k-major: Bs[k][j]

    float acc[4][4];
#pragma unroll
    for (int r = 0; r < 4; ++r)
#pragma unroll
        for (int c = 0; c < 4; ++c) acc[r][c] = 0.f;

    const int srow = t >> 3;        // 0..31 (staging row)
    const int skq  = (t & 7) * 4;   // 0,4,...,28 (staging k offset)

    for (int k0 = 0; k0 < K_DIM; k0 += BK) {
        // coalesced global loads: 8 consecutive lanes cover 128B of one row
        float4 a0 = *(const float4*)(xb + (size_t)srow * K_DIM + k0 + skq);
        float4 a1 = *(const float4*)(xb + (size_t)(srow + 32) * K_DIM + k0 + skq);
        float4 b0 = *(const float4*)(yb + (size_t)srow * K_DIM + k0 + skq);
        float4 b1 = *(const float4*)(yb + (size_t)(srow + 32) * K_DIM + k0 + skq);
        __syncthreads();  // WAR: previous tile's reads done
        As[skq + 0][srow] = a0.x; As[skq + 1][srow] = a0.y;
        As[skq + 2][srow] = a0.z; As[skq + 3][srow] = a0.w;
        As[skq + 0][srow + 32] = a1.x; As[skq + 1][srow + 32] = a1.y;
        As[skq + 2][srow + 32] = a1.z; As[skq + 3][srow + 32] = a1.w;
        Bs[skq + 0][srow] = b0.x; Bs[skq + 1][srow] = b0.y;
        Bs[skq + 2][srow] = b0.z; Bs[skq + 3][srow] = b0.w;
        Bs[skq + 0][srow + 32] = b1.x; Bs[skq + 1][srow + 32] = b1.y;
        Bs[skq + 2][srow + 32] = b1.z; Bs[skq + 3][srow + 32] = b1.w;
        __syncthreads();  // RAW: tile staged

#pragma unroll
        for (int k = 0; k < BK; ++k) {
            float4 av = *(const float4*)(&As[k][ty * 4]);  // ds_read_b128, bcast over tx
            float4 bv = *(const float4*)(&Bs[k][tx * 4]);  // ds_read_b128, 2-way (free)
            float ae[4] = {av.x, av.y, av.z, av.w};
            float be[4] = {bv.x, bv.y, bv.z, bv.w};
#pragma unroll
            for (int r = 0; r < 4; ++r)
#pragma unroll
                for (int c = 0; c < 4; ++c)
                    acc[r][c] = fmaf(ae[r], be[c], acc[r][c]);
        }
    }

    // d(i,j) ordering key: ny[j] - 2*S[i,j]   (x-norm and sqrt are order-preserving)
    float rv[4];
    int   ri[4];
#pragma unroll
    for (int r = 0; r < 4; ++r) { rv[r] = 3.4e38f; ri[r] = 0x7fffffff; }
#pragma unroll
    for (int c = 0; c < 4; ++c) {
        const int jg  = jt * TJ + tx * 4 + c;
        const float nyj = ny[b * C_DIM + jg];
#pragma unroll
        for (int r = 0; r < 4; ++r) {
            const float d = fmaf(-2.f, acc[r][c], nyj);
            if (d < rv[r] || (d == rv[r] && jg < ri[r])) { rv[r] = d; ri[r] = jg; }
        }
    }
    // reduce across the 16 tx lanes (stays inside 16-lane group for masks 1..8)
#pragma unroll
    for (int m = 1; m < 16; m <<= 1) {
#pragma unroll
        for (int r = 0; r < 4; ++r) {
            const float ov = __shfl_xor(rv[r], m, 64);
            const int   oi = __shfl_xor(ri[r], m, 64);
            if (ov < rv[r] || (ov == rv[r] && oi < ri[r])) { rv[r] = ov; ri[r] = oi; }
        }
    }
    if (tx == 0) {
#pragma unroll
        for (int r = 0; r < 4; ++r) {
            const int ig = it * TI + ty * 4 + r;
            const size_t o = ((size_t)b * C_DIM + ig) * 4 + jt;
            pval[o] = rv[r];
            pidx[o] = ri[r];
        }
    }
}

// ---------------- Phase 3: final argmin over 4 tiles + gather winning row ----------------
__global__ __launch_bounds__(256) void gather_kernel(const float* __restrict__ y,
                                                     const float* __restrict__ pval,
                                                     const int* __restrict__ pidx,
                                                     float* __restrict__ out) {
    const int row = blockIdx.x;  // b*C + i
    const int b = row >> 8;
    __shared__ int jsel;
    if (threadIdx.x == 0) {
        float best = pval[(size_t)row * 4];
        int   bi   = pidx[(size_t)row * 4];
#pragma unroll
        for (int jt = 1; jt < 4; ++jt) {
            const float v = pval[(size_t)row * 4 + jt];
            const int   i = pidx[(size_t)row * 4 + jt];
            if (v < best || (v == best && i < bi)) { best = v; bi = i; }
        }
        jsel = bi;
    }
    __syncthreads();
    const float4* src = (const float4*)(y + ((size_t)b * C_DIM + jsel) * K_DIM);
    float4* dst = (float4*)(out + (size_t)row * K_DIM);
    for (int s = threadIdx.x; s < K_DIM / 4; s += 256) dst[s] = src[s];
}

extern "C" void kernel_launch(void* const* d_in, const int* in_sizes, int n_in,
                              void* d_out, int out_size, void* d_ws, size_t ws_size,
                              hipStream_t stream) {
    const float* x = (const float*)d_in[0];   // (B, C, H, W) fp32
    const float* y = (const float*)d_in[1];   // (B, C, H, W) fp32
    float* out = (float*)d_out;               // (B, 256, H, W) fp32

    float* ny   = (float*)d_ws;                          // B*C floats
    float* pval = ny + B_DIM * C_DIM;                    // B*C*4 floats
    int*   pidx = (int*)(pval + B_DIM * C_DIM * 4);      // B*C*4 ints

    norms_kernel<<<B_DIM * C_DIM, 64, 0, stream>>>(y, ny);

    dim3 g2(4, 4, B_DIM);
    gram_argmin_kernel<<<g2, 256, 0, stream>>>(x, y, ny, pval, pidx);

    gather_kernel<<<B_DIM * C_DIM, 256, 0, stream>>>(y, pval, pidx, out);
}

// Round 3
// 315.977 us; speedup vs baseline: 1.1894x; 1.1894x over previous
//
#include <hip/hip_runtime.h>

#define B_DIM 16
#define C_DIM 256
#define K_DIM 4096
#define TAU   0.125f

typedef float f32x4 __attribute__((ext_vector_type(4)));
typedef short s16x8 __attribute__((ext_vector_type(8)));

#define PAD 40   // shorts per LDS row: 32 data + 8 pad -> 80B stride (16B-aligned, uniform banks)
#define BK  32

// ---------------- Phase 1: candidate row norms ny[b*C+j] = ||y_j||^2 (fp32 exact) ----------------
__global__ __launch_bounds__(64) void norms_kernel(const float* __restrict__ y,
                                                   float* __restrict__ ny) {
    const int row = blockIdx.x;  // b*C + j
    const float4* src = (const float4*)(y + (size_t)row * K_DIM);
    float s = 0.f;
    for (int i = threadIdx.x; i < K_DIM / 4; i += 64) {
        float4 v = src[i];
        s += v.x * v.x + v.y * v.y + v.z * v.z + v.w * v.w;
    }
#pragma unroll
    for (int m = 32; m; m >>= 1) s += __shfl_xor(s, m, 64);
    if (threadIdx.x == 0) ny[row] = s;
}

// split fp32 -> truncated-bf16 hi + truncated-bf16 lo (residual); exact enough under recheck
__device__ __forceinline__ void split8(const float4& a, const float4& b,
                                       s16x8& h, s16x8& l) {
    const float f[8] = {a.x, a.y, a.z, a.w, b.x, b.y, b.z, b.w};
#pragma unroll
    for (int i = 0; i < 8; ++i) {
        const unsigned u = __float_as_uint(f[i]);
        const float hf = __uint_as_float(u & 0xFFFF0000u);
        const float r = f[i] - hf;                 // exact (Sterbenz-ish: low mantissa bits)
        h[i] = (short)(u >> 16);
        l[i] = (short)(__float_as_uint(r) >> 16);
    }
}

// ---------------- Phase 2: bf16-split MFMA gram, K-split partials ----------------
// Tile 128x128, 4 waves (each 64x64 = 4x4 frags of 16x16x32), BK=32.
// S ~= Ah*Bh + Ah*Bl + Al*Bh accumulated fp32 in AGPRs.
__global__ __launch_bounds__(256, 2) void gram_kernel(
        const float* __restrict__ x, const float* __restrict__ y,
        float* __restrict__ pS, int ksn, int kper) {
    const int t   = threadIdx.x;
    const int jt  = blockIdx.x;          // 0..1
    const int it  = blockIdx.y;          // 0..1
    const int bz  = blockIdx.z;          // b*ksn + ksi
    const int b   = bz / ksn;
    const int ksi = bz - b * ksn;
    const int kbase = ksi * kper;

    const float* __restrict__ xb = x + ((size_t)b * C_DIM + it * 128) * K_DIM;
    const float* __restrict__ yb = y + ((size_t)b * C_DIM + jt * 128) * K_DIM;

    __shared__ short lds[4][128 * PAD];  // 0=Ah 1=Al 2=Bh 3=Bl  (40 KiB total)

    const int w   = t >> 6;              // wave 0..3
    const int l   = t & 63;
    const int wr  = (w >> 1) * 64;       // wave-out row offset in tile
    const int wc  = (w & 1) * 64;        // wave-out col offset in tile
    const int lr  = l & 15;
    const int lkb = (l >> 4) * 8;        // fragment k offset (shorts)

    f32x4 acc[4][4];
#pragma unroll
    for (int r = 0; r < 4; ++r)
#pragma unroll
        for (int c = 0; c < 4; ++c) acc[r][c] = (f32x4){0.f, 0.f, 0.f, 0.f};

    const int srow = t >> 1;             // 0..127 staging row
    const int sk0  = (t & 1) * 16;       // k base (floats)

    for (int k0 = kbase; k0 < kbase + kper; k0 += BK) {
        __syncthreads();  // WAR: previous tile's fragment reads done
#pragma unroll
        for (int c = 0; c < 2; ++c) {
            const int kq = sk0 + c * 8;  // 8-float chunk
            const float* pa = xb + (size_t)srow * K_DIM + k0 + kq;
            float4 a0 = *(const float4*)pa;
            float4 a1 = *(const float4*)(pa + 4);
            s16x8 h8, l8;
            split8(a0, a1, h8, l8);
            *(s16x8*)&lds[0][srow * PAD + kq] = h8;
            *(s16x8*)&lds[1][srow * PAD + kq] = l8;
            const float* pb = yb + (size_t)srow * K_DIM + k0 + kq;
            float4 b0 = *(const float4*)pb;
            float4 b1 = *(const float4*)(pb + 4);
            split8(b0, b1, h8, l8);
            *(s16x8*)&lds[2][srow * PAD + kq] = h8;
            *(s16x8*)&lds[3][srow * PAD + kq] = l8;
        }
        __syncthreads();  // RAW: tile staged

        s16x8 ah[4], al_[4], bh[4], bl_[4];
#pragma unroll
        for (int r = 0; r < 4; ++r) {
            const int ar = wr + r * 16 + lr;
            ah[r]  = *(const s16x8*)&lds[0][ar * PAD + lkb];
            al_[r] = *(const s16x8*)&lds[1][ar * PAD + lkb];
            const int br = wc + r * 16 + lr;
            bh[r]  = *(const s16x8*)&lds[2][br * PAD + lkb];
            bl_[r] = *(const s16x8*)&lds[3][br * PAD + lkb];
        }
#pragma unroll
        for (int r = 0; r < 4; ++r)
#pragma unroll
            for (int c = 0; c < 4; ++c) {
                acc[r][c] = __builtin_amdgcn_mfma_f32_16x16x32_bf16(ah[r],  bh[c],  acc[r][c], 0, 0, 0);
                acc[r][c] = __builtin_amdgcn_mfma_f32_16x16x32_bf16(ah[r],  bl_[c], acc[r][c], 0, 0, 0);
                acc[r][c] = __builtin_amdgcn_mfma_f32_16x16x32_bf16(al_[r], bh[c],  acc[r][c], 0, 0, 0);
            }
    }

    // partial store: pS[ksi][b][i][j]; D layout: col = lane&15, row = (lane>>4)*4 + e
    float* __restrict__ ps = pS + ((size_t)ksi * B_DIM + b) * (C_DIM * C_DIM);
#pragma unroll
    for (int r = 0; r < 4; ++r)
#pragma unroll
        for (int c = 0; c < 4; ++c) {
            const int jg = jt * 128 + wc + c * 16 + lr;
#pragma unroll
            for (int e = 0; e < 4; ++e) {
                const int ig = it * 128 + wr + r * 16 + (l >> 4) * 4 + e;
                ps[(size_t)ig * C_DIM + jg] = acc[r][c][e];
            }
        }
}

// ---------------- Phase 3: reduce partials + argmin(top2) + exact recheck + gather ----------------
__global__ __launch_bounds__(256) void finale_kernel(
        const float* __restrict__ x, const float* __restrict__ y,
        const float* __restrict__ pS, const float* __restrict__ ny,
        float* __restrict__ out, int ksn) {
    const int row = blockIdx.x;   // b*C + i
    const int b = row >> 8;
    const int i = row & 255;
    const int j = threadIdx.x;    // candidate index

    __shared__ float ds[C_DIM];
    __shared__ int   ish[C_DIM];
    __shared__ float xrow[K_DIM];

    float s = 0.f;
    for (int ksi = 0; ksi < ksn; ++ksi)
        s += pS[((size_t)ksi * B_DIM + b) * (C_DIM * C_DIM) + (size_t)i * C_DIM + j];
    const float d = fmaf(-2.f, s, ny[b * C_DIM + j]);  // ordering key (nx, sqrt monotone)

    ds[j] = d; ish[j] = j;
    __syncthreads();
#pragma unroll
    for (int off = 128; off; off >>= 1) {
        if (j < off) {
            const float dv = ds[j + off]; const int iv = ish[j + off];
            if (dv < ds[j] || (dv == ds[j] && iv < ish[j])) { ds[j] = dv; ish[j] = iv; }
        }
        __syncthreads();
    }
    const int   best1 = ish[0];
    const float bestv = ds[0];
    __syncthreads();

    // second-best (masked re-run) for the gap
    ds[j] = (j == best1) ? 3.4e38f : d;
    __syncthreads();
#pragma unroll
    for (int off = 128; off; off >>= 1) {
        if (j < off) { const float dv = ds[j + off]; if (dv < ds[j]) ds[j] = dv; }
        __syncthreads();
    }
    int bestj = best1;

    if (ds[0] - bestv < TAU) {  // near-tie: exact fp32 re-decision (block-uniform branch)
        const float4* xs = (const float4*)(x + ((size_t)b * C_DIM + i) * K_DIM);
        for (int k = j; k < K_DIM / 4; k += 256) ((float4*)xrow)[k] = xs[k];
        __syncthreads();
        const float4* yr = (const float4*)(y + ((size_t)b * C_DIM + j) * K_DIM);
        float ax = 0.f, ay = 0.f, az = 0.f, aw = 0.f;
        for (int k = 0; k < K_DIM / 4; ++k) {
            const float4 yv = yr[k];
            const float4 xv = ((const float4*)xrow)[k];
            const float d0 = xv.x - yv.x; ax = fmaf(d0, d0, ax);
            const float d1 = xv.y - yv.y; ay = fmaf(d1, d1, ay);
            const float d2 = xv.z - yv.z; az = fmaf(d2, d2, az);
            const float d3 = xv.w - yv.w; aw = fmaf(d3, d3, aw);
        }
        const float de = (ax + ay) + (az + aw);
        __syncthreads();
        ds[j] = de; ish[j] = j;
        __syncthreads();
#pragma unroll
        for (int off = 128; off; off >>= 1) {
            if (j < off) {
                const float dv = ds[j + off]; const int iv = ish[j + off];
                if (dv < ds[j] || (dv == ds[j] && iv < ish[j])) { ds[j] = dv; ish[j] = iv; }
            }
            __syncthreads();
        }
        bestj = ish[0];
    }
    __syncthreads();

    // gather winning candidate row
    const float4* src = (const float4*)(y + ((size_t)b * C_DIM + bestj) * K_DIM);
    float4* dst = (float4*)(out + (size_t)row * K_DIM);
    for (int k = j; k < K_DIM / 4; k += 256) dst[k] = src[k];
}

extern "C" void kernel_launch(void* const* d_in, const int* in_sizes, int n_in,
                              void* d_out, int out_size, void* d_ws, size_t ws_size,
                              hipStream_t stream) {
    const float* x = (const float*)d_in[0];   // (B, C, H, W) fp32
    const float* y = (const float*)d_in[1];   // (B, C, H, W) fp32
    float* out = (float*)d_out;

    // pick K-split by available workspace: pS = ksn*16MB + ny 16KB
    int ksn = 8;
    while (ksn > 1) {
        const size_t need = ((size_t)ksn * B_DIM * C_DIM * C_DIM + B_DIM * C_DIM) * 4;
        if (need <= ws_size) break;
        ksn >>= 1;
    }
    float* pS = (float*)d_ws;
    float* ny = pS + (size_t)ksn * B_DIM * C_DIM * C_DIM;

    norms_kernel<<<B_DIM * C_DIM, 64, 0, stream>>>(y, ny);

    dim3 g2(2, 2, B_DIM * ksn);
    gram_kernel<<<g2, 256, 0, stream>>>(x, y, pS, ksn, K_DIM / ksn);

    finale_kernel<<<B_DIM * C_DIM, 256, 0, stream>>>(x, y, pS, ny, out, ksn);
}

// Round 4
// 212.627 us; speedup vs baseline: 1.7676x; 1.4861x over previous
//
#include <hip/hip_runtime.h>

#define B_DIM 16
#define C_DIM 256
#define K_DIM 4096
#define TAU   0.125f

typedef float f32x4 __attribute__((ext_vector_type(4)));
typedef short s16x8 __attribute__((ext_vector_type(8)));

#define PAD 40   // shorts per LDS row: 32 data + 8 pad -> 80B stride (16B-aligned, uniform banks)
#define BK  32

// ---------------- Phase 1: candidate row norms ny[b*C+j] = ||y_j||^2 (fp32 exact) ----------------
__global__ __launch_bounds__(64) void norms_kernel(const float* __restrict__ y,
                                                   float* __restrict__ ny) {
    const int row = blockIdx.x;  // b*C + j
    const float4* src = (const float4*)(y + (size_t)row * K_DIM);
    float s = 0.f;
    for (int i = threadIdx.x; i < K_DIM / 4; i += 64) {
        float4 v = src[i];
        s += v.x * v.x + v.y * v.y + v.z * v.z + v.w * v.w;
    }
#pragma unroll
    for (int m = 32; m; m >>= 1) s += __shfl_xor(s, m, 64);
    if (threadIdx.x == 0) ny[row] = s;
}

// split fp32 -> truncated-bf16 hi + truncated-bf16 lo (residual)
__device__ __forceinline__ void split8(const float4& a, const float4& b,
                                       s16x8& h, s16x8& l) {
    const float f[8] = {a.x, a.y, a.z, a.w, b.x, b.y, b.z, b.w};
#pragma unroll
    for (int i = 0; i < 8; ++i) {
        const unsigned u = __float_as_uint(f[i]);
        const float hf = __uint_as_float(u & 0xFFFF0000u);
        const float r = f[i] - hf;
        h[i] = (short)(u >> 16);
        l[i] = (short)(__float_as_uint(r) >> 16);
    }
}

// ---------------- Phase 2: bf16-split MFMA gram, K-split partials (UNCHANGED) ----------------
__global__ __launch_bounds__(256, 2) void gram_kernel(
        const float* __restrict__ x, const float* __restrict__ y,
        float* __restrict__ pS, int ksn, int kper) {
    const int t   = threadIdx.x;
    const int jt  = blockIdx.x;
    const int it  = blockIdx.y;
    const int bz  = blockIdx.z;
    const int b   = bz / ksn;
    const int ksi = bz - b * ksn;
    const int kbase = ksi * kper;

    const float* __restrict__ xb = x + ((size_t)b * C_DIM + it * 128) * K_DIM;
    const float* __restrict__ yb = y + ((size_t)b * C_DIM + jt * 128) * K_DIM;

    __shared__ short lds[4][128 * PAD];

    const int w   = t >> 6;
    const int l   = t & 63;
    const int wr  = (w >> 1) * 64;
    const int wc  = (w & 1) * 64;
    const int lr  = l & 15;
    const int lkb = (l >> 4) * 8;

    f32x4 acc[4][4];
#pragma unroll
    for (int r = 0; r < 4; ++r)
#pragma unroll
        for (int c = 0; c < 4; ++c) acc[r][c] = (f32x4){0.f, 0.f, 0.f, 0.f};

    const int srow = t >> 1;
    const int sk0  = (t & 1) * 16;

    for (int k0 = kbase; k0 < kbase + kper; k0 += BK) {
        __syncthreads();
#pragma unroll
        for (int c = 0; c < 2; ++c) {
            const int kq = sk0 + c * 8;
            const float* pa = xb + (size_t)srow * K_DIM + k0 + kq;
            float4 a0 = *(const float4*)pa;
            float4 a1 = *(const float4*)(pa + 4);
            s16x8 h8, l8;
            split8(a0, a1, h8, l8);
            *(s16x8*)&lds[0][srow * PAD + kq] = h8;
            *(s16x8*)&lds[1][srow * PAD + kq] = l8;
            const float* pb = yb + (size_t)srow * K_DIM + k0 + kq;
            float4 b0 = *(const float4*)pb;
            float4 b1 = *(const float4*)(pb + 4);
            split8(b0, b1, h8, l8);
            *(s16x8*)&lds[2][srow * PAD + kq] = h8;
            *(s16x8*)&lds[3][srow * PAD + kq] = l8;
        }
        __syncthreads();

        s16x8 ah[4], al_[4], bh[4], bl_[4];
#pragma unroll
        for (int r = 0; r < 4; ++r) {
            const int ar = wr + r * 16 + lr;
            ah[r]  = *(const s16x8*)&lds[0][ar * PAD + lkb];
            al_[r] = *(const s16x8*)&lds[1][ar * PAD + lkb];
            const int br = wc + r * 16 + lr;
            bh[r]  = *(const s16x8*)&lds[2][br * PAD + lkb];
            bl_[r] = *(const s16x8*)&lds[3][br * PAD + lkb];
        }
#pragma unroll
        for (int r = 0; r < 4; ++r)
#pragma unroll
            for (int c = 0; c < 4; ++c) {
                acc[r][c] = __builtin_amdgcn_mfma_f32_16x16x32_bf16(ah[r],  bh[c],  acc[r][c], 0, 0, 0);
                acc[r][c] = __builtin_amdgcn_mfma_f32_16x16x32_bf16(ah[r],  bl_[c], acc[r][c], 0, 0, 0);
                acc[r][c] = __builtin_amdgcn_mfma_f32_16x16x32_bf16(al_[r], bh[c],  acc[r][c], 0, 0, 0);
            }
    }

    float* __restrict__ ps = pS + ((size_t)ksi * B_DIM + b) * (C_DIM * C_DIM);
#pragma unroll
    for (int r = 0; r < 4; ++r)
#pragma unroll
        for (int c = 0; c < 4; ++c) {
            const int jg = jt * 128 + wc + c * 16 + lr;
#pragma unroll
            for (int e = 0; e < 4; ++e) {
                const int ig = it * 128 + wr + r * 16 + (l >> 4) * 4 + e;
                ps[(size_t)ig * C_DIM + jg] = acc[r][c][e];
            }
        }
}

// ---------------- Phase 3: wave-per-row reduce + top2 + exact recheck + gather ----------------
// No LDS, no barriers. 1024 blocks x 4 waves; wave w owns row = blockIdx.x*4 + w.
__global__ __launch_bounds__(256) void reduce_gather_kernel(
        const float* __restrict__ x, const float* __restrict__ y,
        const float* __restrict__ pS, const float* __restrict__ ny,
        float* __restrict__ out, int ksn) {
    const int w    = threadIdx.x >> 6;
    const int lane = threadIdx.x & 63;
    const int row  = blockIdx.x * 4 + w;   // b*C + i
    const int b    = row >> 8;
    const int i    = row & 255;

    // each lane owns candidates j = lane*4 .. lane*4+3 (one float4 per ksi, coalesced)
    f32x4 s = {0.f, 0.f, 0.f, 0.f};
    for (int ksi = 0; ksi < ksn; ++ksi) {
        const float4 v = *(const float4*)(pS +
            ((size_t)ksi * B_DIM + b) * (C_DIM * C_DIM) + (size_t)i * C_DIM + lane * 4);
        s[0] += v.x; s[1] += v.y; s[2] += v.z; s[3] += v.w;
    }
    const float4 nyv = *(const float4*)(ny + b * C_DIM + lane * 4);
    float d[4];
    d[0] = fmaf(-2.f, s[0], nyv.x);
    d[1] = fmaf(-2.f, s[1], nyv.y);
    d[2] = fmaf(-2.f, s[2], nyv.z);
    d[3] = fmaf(-2.f, s[3], nyv.w);

    // lane-local top-2 (ascending j => strict < keeps lowest index)
    float best = d[0], second = 3.4e38f;
    int   bidx = lane * 4;
#pragma unroll
    for (int q = 1; q < 4; ++q) {
        if (d[q] < best) { second = best; best = d[q]; bidx = lane * 4 + q; }
        else if (d[q] < second) second = d[q];
    }
    // butterfly top-2 merge across 64 lanes (all lanes converge)
#pragma unroll
    for (int m = 1; m < 64; m <<= 1) {
        const float ob = __shfl_xor(best, m, 64);
        const int   oi = __shfl_xor(bidx, m, 64);
        const float os = __shfl_xor(second, m, 64);
        if (ob < best || (ob == best && oi < bidx)) {
            second = fminf(best, os);
            best = ob; bidx = oi;
        } else {
            second = fminf(second, ob);
        }
    }

    int bestj = bidx;
    if (second - best < TAU) {
        // exact fp32 re-decision over flagged candidates (includes best1 since d-best==0)
        const float* xr = x + ((size_t)b * C_DIM + i) * K_DIM;
        float ebest = 3.4e38f;
        int   ebj   = 0x7fffffff;
#pragma unroll
        for (int q = 0; q < 4; ++q) {
            unsigned long long msk = __ballot(d[q] - best < TAU);
            while (msk) {
                const int L = __ffsll((unsigned long long)msk) - 1;
                msk &= msk - 1;
                const int j = L * 4 + q;
                const float* yr = y + ((size_t)b * C_DIM + j) * K_DIM;
                float a0 = 0.f, a1 = 0.f, a2 = 0.f, a3 = 0.f;
                for (int c = 0; c < 16; ++c) {
                    const float4 xv = *(const float4*)(xr + (c * 64 + lane) * 4);
                    const float4 yv = *(const float4*)(yr + (c * 64 + lane) * 4);
                    const float e0 = xv.x - yv.x; a0 = fmaf(e0, e0, a0);
                    const float e1 = xv.y - yv.y; a1 = fmaf(e1, e1, a1);
                    const float e2 = xv.z - yv.z; a2 = fmaf(e2, e2, a2);
                    const float e3 = xv.w - yv.w; a3 = fmaf(e3, e3, a3);
                }
                float de = (a0 + a1) + (a2 + a3);
#pragma unroll
                for (int m = 1; m < 64; m <<= 1) de += __shfl_xor(de, m, 64);
                if (de < ebest || (de == ebest && j < ebj)) { ebest = de; ebj = j; }
            }
        }
        bestj = ebj;
    }

    // gather: wave copies its winning 16 KB row (16 x 1KB coalesced)
    const float4* src = (const float4*)(y + ((size_t)b * C_DIM + bestj) * K_DIM);
    float4* dst = (float4*)(out + (size_t)row * K_DIM);
#pragma unroll
    for (int c = 0; c < 16; ++c) dst[c * 64 + lane] = src[c * 64 + lane];
}

extern "C" void kernel_launch(void* const* d_in, const int* in_sizes, int n_in,
                              void* d_out, int out_size, void* d_ws, size_t ws_size,
                              hipStream_t stream) {
    const float* x = (const float*)d_in[0];   // (B, C, H, W) fp32
    const float* y = (const float*)d_in[1];   // (B, C, H, W) fp32
    float* out = (float*)d_out;

    int ksn = 8;
    while (ksn > 1) {
        const size_t need = ((size_t)ksn * B_DIM * C_DIM * C_DIM + B_DIM * C_DIM) * 4;
        if (need <= ws_size) break;
        ksn >>= 1;
    }
    float* pS = (float*)d_ws;
    float* ny = pS + (size_t)ksn * B_DIM * C_DIM * C_DIM;

    norms_kernel<<<B_DIM * C_DIM, 64, 0, stream>>>(y, ny);

    dim3 g2(2, 2, B_DIM * ksn);
    gram_kernel<<<g2, 256, 0, stream>>>(x, y, pS, ksn, K_DIM / ksn);

    reduce_gather_kernel<<<B_DIM * C_DIM / 4, 256, 0, stream>>>(x, y, pS, ny, out, ksn);
}